// Round 7
// baseline (238.202 us; speedup 1.0000x reference)
//
#include <hip/hip_runtime.h>

#define CNT    2048
#define TPB    256
#define BLOCKS 1024          // 4096 waves, 4 items each -> all resident, deep steady state
#define WPB    (TPB / 64)
#define SEGS   4             // 512 steps per segment, 8 steps per lane

typedef float fx4 __attribute__((ext_vector_type(4)));   // native vec for nontemporal builtins

struct Q { float w, x, y, z; };

__device__ __forceinline__ Q qmul(const Q a, const Q b) {
    Q o;
    o.w = a.w*b.w - a.x*b.x - a.y*b.y - a.z*b.z;
    o.x = a.w*b.x + a.x*b.w + a.y*b.z - a.z*b.y;
    o.y = a.w*b.y - a.x*b.z + a.y*b.w + a.z*b.x;
    o.z = a.w*b.z + a.x*b.y - a.y*b.x + a.z*b.w;
    return o;
}
__device__ __forceinline__ Q qmul1(const Q a, const float bx, const float by, const float bz) {
    Q o;
    o.w = a.w - (a.x*bx + a.y*by + a.z*bz);
    o.x = a.x + (a.w*bx + a.y*bz - a.z*by);
    o.y = a.y + (a.w*by - a.x*bz + a.z*bx);
    o.z = a.z + (a.w*bz + a.x*by - a.y*bx);
    return o;
}

__device__ __forceinline__ fx4   ldnt4(const void* p) { return __builtin_nontemporal_load((const fx4*)p); }
__device__ __forceinline__ float ldnt1(const float* p) { return __builtin_nontemporal_load(p); }

template<bool FAST>
__device__ __forceinline__ void gf_eval(const float* rg, int k,
        const float* w1, const float* bb1, float a1,
        const float* w2, const float* bb2, float a2,
        float& gx, float& gy, float& gz)
{
    const float vx = rg[3*k + 0], vy = rg[3*k + 1], vz = rg[3*k + 2];
    float h0, h1, h2;
    if (FAST) { h0 = vx; h1 = vy; h2 = vz; }
    else {
        h0 = w1[0]*vx + w1[1]*vy + w1[2]*vz + bb1[0];
        h1 = w1[3]*vx + w1[4]*vy + w1[5]*vz + bb1[1];
        h2 = w1[6]*vx + w1[7]*vy + w1[8]*vz + bb1[2];
    }
    h0 = h0 >= 0.0f ? h0 : a1 * h0;
    h1 = h1 >= 0.0f ? h1 : a1 * h1;
    h2 = h2 >= 0.0f ? h2 : a1 * h2;
    float u0, u1, u2;
    if (FAST) { u0 = h0; u1 = h1; u2 = h2; }
    else {
        u0 = w2[0]*h0 + w2[1]*h1 + w2[2]*h2 + bb2[0];
        u1 = w2[3]*h0 + w2[4]*h1 + w2[5]*h2 + bb2[1];
        u2 = w2[6]*h0 + w2[7]*h1 + w2[8]*h2 + bb2[2];
    }
    u0 = u0 >= 0.0f ? u0 : a2 * u0;
    u1 = u1 >= 0.0f ? u1 : a2 * u1;
    u2 = u2 >= 0.0f ? u2 : a2 * u2;
    gx = u0 + vx; gy = u1 + vy; gz = u2 + vz;
}

// ordered product of this lane's 8 steps + ordered 64-lane shuffle reduction
template<bool FAST>
__device__ __forceinline__ Q seg_product(const float* rg, const float* rt,
        const float* w1, const float* bb1, float a1,
        const float* w2, const float* bb2, float a2)
{
    Q P = {1.0f, 0.0f, 0.0f, 0.0f};
    float g0x, g0y, g0z;
    gf_eval<FAST>(rg, 0, w1, bb1, a1, w2, bb2, a2, g0x, g0y, g0z);
    #pragma unroll
    for (int j = 0; j < 8; ++j) {
        float g1x, g1y, g1z;
        gf_eval<FAST>(rg, j + 1, w1, bb1, a1, w2, bb2, a2, g1x, g1y, g1z);
        const float sc = 0.25f * (rt[j + 1] - rt[j]);
        P = qmul1(P, (g0x + g1x) * sc, (g0y + g1y) * sc, (g0z + g1z) * sc);
        g0x = g1x; g0y = g1y; g0z = g1z;
    }
    const float n2  = P.w*P.w + P.x*P.x + P.y*P.y + P.z*P.z;
    const float inv = 1.0f / sqrtf(n2);          // n2 >= 1 always
    P.w *= inv; P.x *= inv; P.y *= inv; P.z *= inv;
    #pragma unroll
    for (int sft = 1; sft < 64; sft <<= 1) {
        Q o;
        o.w = __shfl_down(P.w, sft);
        o.x = __shfl_down(P.x, sft);
        o.y = __shfl_down(P.y, sft);
        o.z = __shfl_down(P.z, sft);
        P = qmul(P, o);
    }
    return P;                                     // lane 0 holds the ordered product
}

__global__ __launch_bounds__(TPB, 4) void pass1_kernel(
    const float* __restrict__ ts,    // (B, CNT)
    const float* __restrict__ gyro,  // (B, CNT, 3)
    const float* __restrict__ W1, const float* __restrict__ b1, const float* __restrict__ a1p,
    const float* __restrict__ W2, const float* __restrict__ b2, const float* __restrict__ a2p,
    float4* __restrict__ ws,         // (B*SEGS) partial quats
    int nitems)
{
    const int lane = threadIdx.x & 63;
    const int wgid = blockIdx.x * WPB + (threadIdx.x >> 6);
    const int nw   = gridDim.x * WPB;

    float w1[9], w2[9], bb1[3], bb2[3];
    #pragma unroll
    for (int i = 0; i < 9; ++i) { w1[i] = W1[i]; w2[i] = W2[i]; }
    #pragma unroll
    for (int i = 0; i < 3; ++i) { bb1[i] = b1[i]; bb2[i] = b2[i]; }
    const float a1 = a1p[0], a2 = a2p[0];

    // identity fast-path flag (uniform); fast path exactly equivalent when it holds
    float dev = 0.0f;
    #pragma unroll
    for (int i = 0; i < 9; ++i) {
        const float id = (i == 0 || i == 4 || i == 8) ? 1.0f : 0.0f;
        dev += fabsf(w1[i] - id) + fabsf(w2[i] - id);
    }
    #pragma unroll
    for (int i = 0; i < 3; ++i) dev += fabsf(bb1[i]) + fabsf(bb2[i]);
    const bool fast = (dev == 0.0f);

    // item = (row r, seg s): lane covers steps [512s + 8*lane, +8)
    auto loadit = [&](int item, float* rg, float* rt) {
        const int r = item >> 2, s = item & 3;
        const bool last = (s == 3) && (lane == 63);   // owns nonexistent step t=2047
        const float* gp = (const float*)(gyro + (size_t)r * (CNT * 3)) + 4 * (384 * s + 6 * lane);
        #pragma unroll
        for (int k = 0; k < 6; ++k) *(fx4*)(rg + 4*k) = ldnt4(gp + 4*k);
        // pad sample: clamp ADDRESS (no OOB, value finite); dt=0 makes the step identity
        *(fx4*)(rg + 24) = ldnt4(gp + 4 * (last ? 5 : 6));
        const float* trow = ts + (size_t)r * CNT + (512 * s + 8 * lane);
        *(fx4*)(rt + 0) = ldnt4(trow);
        *(fx4*)(rt + 4) = ldnt4(trow + 4);
        rt[8] = ldnt1(trow + (last ? 7 : 8));         // last: rt[8]==rt[7] -> dt=0
    };

    auto emit = [&](int item, const Q& P) {
        if (lane == 0) ws[item] = make_float4(P.w, P.x, P.y, P.z);
    };

    // ---- ping-pong software pipeline: no buffer copies, prefetch never drained early
    float rgA[28], rtA[9], rgB[28], rtB[9];
    if (wgid < nitems) loadit(wgid, rgA, rtA);

    for (int k = wgid; k < nitems; k += 2 * nw) {
        const int kB = k + nw;
        if (kB < nitems) loadit(kB, rgB, rtB);        // in flight during compute(A)
        {
            Q P = fast ? seg_product<true >(rgA, rtA, w1, bb1, a1, w2, bb2, a2)
                       : seg_product<false>(rgA, rtA, w1, bb1, a1, w2, bb2, a2);
            emit(k, P);
        }
        const int kA = k + 2 * nw;
        if (kA < nitems) loadit(kA, rgA, rtA);        // in flight during compute(B)
        if (kB < nitems) {
            Q P = fast ? seg_product<true >(rgB, rtB, w1, bb1, a1, w2, bb2, a2)
                       : seg_product<false>(rgB, rtB, w1, bb1, a1, w2, bb2, a2);
            emit(kB, P);
        }
    }
}

__global__ __launch_bounds__(TPB) void pass2_kernel(
    const float4* __restrict__ ws,   // (B*SEGS) partials in segment order
    const float*  __restrict__ sq,   // (B, 4)
    float* __restrict__ out, int B)
{
    const int r = blockIdx.x * blockDim.x + threadIdx.x;
    if (r >= B) return;
    float4 p0 = ws[4*r + 0];
    Q acc = {p0.x, p0.y, p0.z, p0.w};
    #pragma unroll
    for (int k = 1; k < 4; ++k) {
        const float4 pk = ws[4*r + k];
        const Q qk = {pk.x, pk.y, pk.z, pk.w};
        acc = qmul(acc, qk);
    }
    const float4 s0 = ((const float4*)sq)[r];
    const Q q0 = {s0.x, s0.y, s0.z, s0.w};
    Q qf = qmul(q0, acc);
    const float n   = sqrtf(qf.w*qf.w + qf.x*qf.x + qf.y*qf.y + qf.z*qf.z);
    const float inv = 1.0f / fmaxf(n, 1e-12f);
    float4 o;
    o.x = qf.w * inv; o.y = qf.x * inv; o.z = qf.y * inv; o.w = qf.z * inv;
    ((float4*)out)[r] = o;
}

extern "C" void kernel_launch(void* const* d_in, const int* in_sizes, int n_in,
                              void* d_out, int out_size, void* d_ws, size_t ws_size,
                              hipStream_t stream) {
    const float* ts   = (const float*)d_in[0];
    const float* gyro = (const float*)d_in[1];
    const float* sq   = (const float*)d_in[2];
    const float* W1   = (const float*)d_in[3];
    const float* b1   = (const float*)d_in[4];
    const float* a1   = (const float*)d_in[5];
    const float* W2   = (const float*)d_in[6];
    const float* b2   = (const float*)d_in[7];
    const float* a2   = (const float*)d_in[8];
    float* out = (float*)d_out;

    const int B      = in_sizes[0] / CNT;   // 4096
    const int nitems = B * SEGS;            // 16384
    float4* ws = (float4*)d_ws;             // 256 KB

    pass1_kernel<<<BLOCKS, TPB, 0, stream>>>(ts, gyro, W1, b1, a1, W2, b2, a2, ws, nitems);
    pass2_kernel<<<(B + TPB - 1) / TPB, TPB, 0, stream>>>(ws, sq, out, B);
}

// Round 8
// 212.293 us; speedup vs baseline: 1.1220x; 1.1220x over previous
//
#include <hip/hip_runtime.h>

#define CNT    2048
#define TPB    256
#define BLOCKS 1024          // 4096 waves, 4 items each -> all resident, deep steady state
#define WPB    (TPB / 64)
#define SEGS   4             // 512 steps per segment, 8 steps per lane

typedef float fx4 __attribute__((ext_vector_type(4)));

struct Q { float w, x, y, z; };

__device__ __forceinline__ Q qmul(const Q a, const Q b) {
    Q o;
    o.w = a.w*b.w - a.x*b.x - a.y*b.y - a.z*b.z;
    o.x = a.w*b.x + a.x*b.w + a.y*b.z - a.z*b.y;
    o.y = a.w*b.y - a.x*b.z + a.y*b.w + a.z*b.x;
    o.z = a.w*b.z + a.x*b.y - a.y*b.x + a.z*b.w;
    return o;
}
__device__ __forceinline__ Q qmul1(const Q a, const float bx, const float by, const float bz) {
    Q o;
    o.w = a.w - (a.x*bx + a.y*by + a.z*bz);
    o.x = a.x + (a.w*bx + a.y*bz - a.z*by);
    o.y = a.y + (a.w*by - a.x*bz + a.z*bx);
    o.z = a.z + (a.w*bz + a.x*by - a.y*bx);
    return o;
}

template<bool FAST>
__device__ __forceinline__ void gf_eval(const float* rg, int k,
        const float* w1, const float* bb1, float a1,
        const float* w2, const float* bb2, float a2,
        float& gx, float& gy, float& gz)
{
    const float vx = rg[3*k + 0], vy = rg[3*k + 1], vz = rg[3*k + 2];
    float h0, h1, h2;
    if (FAST) { h0 = vx; h1 = vy; h2 = vz; }
    else {
        h0 = w1[0]*vx + w1[1]*vy + w1[2]*vz + bb1[0];
        h1 = w1[3]*vx + w1[4]*vy + w1[5]*vz + bb1[1];
        h2 = w1[6]*vx + w1[7]*vy + w1[8]*vz + bb1[2];
    }
    h0 = h0 >= 0.0f ? h0 : a1 * h0;
    h1 = h1 >= 0.0f ? h1 : a1 * h1;
    h2 = h2 >= 0.0f ? h2 : a1 * h2;
    float u0, u1, u2;
    if (FAST) { u0 = h0; u1 = h1; u2 = h2; }
    else {
        u0 = w2[0]*h0 + w2[1]*h1 + w2[2]*h2 + bb2[0];
        u1 = w2[3]*h0 + w2[4]*h1 + w2[5]*h2 + bb2[1];
        u2 = w2[6]*h0 + w2[7]*h1 + w2[8]*h2 + bb2[2];
    }
    u0 = u0 >= 0.0f ? u0 : a2 * u0;
    u1 = u1 >= 0.0f ? u1 : a2 * u1;
    u2 = u2 >= 0.0f ? u2 : a2 * u2;
    gx = u0 + vx; gy = u1 + vy; gz = u2 + vz;
}

// ordered product of this lane's 8 steps + ordered 64-lane shuffle reduction
template<bool FAST>
__device__ __forceinline__ Q seg_product(const float* rg, const float* rt,
        const float* w1, const float* bb1, float a1,
        const float* w2, const float* bb2, float a2)
{
    Q P = {1.0f, 0.0f, 0.0f, 0.0f};
    float g0x, g0y, g0z;
    gf_eval<FAST>(rg, 0, w1, bb1, a1, w2, bb2, a2, g0x, g0y, g0z);
    #pragma unroll
    for (int j = 0; j < 8; ++j) {
        float g1x, g1y, g1z;
        gf_eval<FAST>(rg, j + 1, w1, bb1, a1, w2, bb2, a2, g1x, g1y, g1z);
        const float sc = 0.25f * (rt[j + 1] - rt[j]);
        P = qmul1(P, (g0x + g1x) * sc, (g0y + g1y) * sc, (g0z + g1z) * sc);
        g0x = g1x; g0y = g1y; g0z = g1z;
    }
    const float n2  = P.w*P.w + P.x*P.x + P.y*P.y + P.z*P.z;
    const float inv = 1.0f / sqrtf(n2);          // n2 >= 1 always
    P.w *= inv; P.x *= inv; P.y *= inv; P.z *= inv;
    #pragma unroll
    for (int sft = 1; sft < 64; sft <<= 1) {
        Q o;
        o.w = __shfl_down(P.w, sft);
        o.x = __shfl_down(P.x, sft);
        o.y = __shfl_down(P.y, sft);
        o.z = __shfl_down(P.z, sft);
        P = qmul(P, o);
    }
    return P;                                     // lane 0 holds the ordered product
}

__global__ __launch_bounds__(TPB, 4) void pass1_kernel(
    const float* __restrict__ ts,    // (B, CNT)
    const float* __restrict__ gyro,  // (B, CNT, 3)
    const float* __restrict__ W1, const float* __restrict__ b1, const float* __restrict__ a1p,
    const float* __restrict__ W2, const float* __restrict__ b2, const float* __restrict__ a2p,
    float4* __restrict__ ws,         // (B*SEGS) partial quats
    int nitems)
{
    const int lane = threadIdx.x & 63;
    const int wgid = blockIdx.x * WPB + (threadIdx.x >> 6);
    const int nw   = gridDim.x * WPB;

    float w1[9], w2[9], bb1[3], bb2[3];
    #pragma unroll
    for (int i = 0; i < 9; ++i) { w1[i] = W1[i]; w2[i] = W2[i]; }
    #pragma unroll
    for (int i = 0; i < 3; ++i) { bb1[i] = b1[i]; bb2[i] = b2[i]; }
    const float a1 = a1p[0], a2 = a2p[0];

    // identity fast-path flag (uniform); fast path exactly equivalent when it holds
    float dev = 0.0f;
    #pragma unroll
    for (int i = 0; i < 9; ++i) {
        const float id = (i == 0 || i == 4 || i == 8) ? 1.0f : 0.0f;
        dev += fabsf(w1[i] - id) + fabsf(w2[i] - id);
    }
    #pragma unroll
    for (int i = 0; i < 3; ++i) dev += fabsf(bb1[i]) + fabsf(bb2[i]);
    const bool fast = (dev == 0.0f);

    // item = (row r, seg s): lane covers steps [512s + 8*lane, +8)
    auto loadit = [&](int item, float* rg, float* rt) {
        const int r = item >> 2, s = item & 3;
        const bool last = (s == 3) && (lane == 63);   // owns nonexistent step t=2047
        const float* gp = (const float*)(gyro + (size_t)r * (CNT * 3)) + 4 * (384 * s + 6 * lane);
        #pragma unroll
        for (int k = 0; k < 6; ++k) *(fx4*)(rg + 4*k) = *(const fx4*)(gp + 4*k);
        // pad sample: clamp ADDRESS (no OOB, value finite); dt=0 makes the step identity
        *(fx4*)(rg + 24) = *(const fx4*)(gp + 4 * (last ? 5 : 6));
        const float* trow = ts + (size_t)r * CNT + (512 * s + 8 * lane);
        *(fx4*)(rt + 0) = *(const fx4*)trow;
        *(fx4*)(rt + 4) = *(const fx4*)(trow + 4);
        rt[8] = trow[last ? 7 : 8];                   // last: rt[8]==rt[7] -> dt=0
    };

    auto emit = [&](int item, const Q& P) {
        if (lane == 0) ws[item] = make_float4(P.w, P.x, P.y, P.z);
    };

    // ---- ping-pong software pipeline: no buffer copies, prefetch never drained early
    float rgA[28], rtA[9], rgB[28], rtB[9];
    if (wgid < nitems) loadit(wgid, rgA, rtA);

    for (int k = wgid; k < nitems; k += 2 * nw) {
        const int kB = k + nw;
        if (kB < nitems) loadit(kB, rgB, rtB);        // in flight during compute(A)
        {
            Q P = fast ? seg_product<true >(rgA, rtA, w1, bb1, a1, w2, bb2, a2)
                       : seg_product<false>(rgA, rtA, w1, bb1, a1, w2, bb2, a2);
            emit(k, P);
        }
        const int kA = k + 2 * nw;
        if (kA < nitems) loadit(kA, rgA, rtA);        // in flight during compute(B)
        if (kB < nitems) {
            Q P = fast ? seg_product<true >(rgB, rtB, w1, bb1, a1, w2, bb2, a2)
                       : seg_product<false>(rgB, rtB, w1, bb1, a1, w2, bb2, a2);
            emit(kB, P);
        }
    }
}

__global__ __launch_bounds__(TPB) void pass2_kernel(
    const float4* __restrict__ ws,   // (B*SEGS) partials in segment order
    const float*  __restrict__ sq,   // (B, 4)
    float* __restrict__ out, int B)
{
    const int r = blockIdx.x * blockDim.x + threadIdx.x;
    if (r >= B) return;
    float4 p0 = ws[4*r + 0];
    Q acc = {p0.x, p0.y, p0.z, p0.w};
    #pragma unroll
    for (int k = 1; k < 4; ++k) {
        const float4 pk = ws[4*r + k];
        const Q qk = {pk.x, pk.y, pk.z, pk.w};
        acc = qmul(acc, qk);
    }
    const float4 s0 = ((const float4*)sq)[r];
    const Q q0 = {s0.x, s0.y, s0.z, s0.w};
    Q qf = qmul(q0, acc);
    const float n   = sqrtf(qf.w*qf.w + qf.x*qf.x + qf.y*qf.y + qf.z*qf.z);
    const float inv = 1.0f / fmaxf(n, 1e-12f);
    float4 o;
    o.x = qf.w * inv; o.y = qf.x * inv; o.z = qf.y * inv; o.w = qf.z * inv;
    ((float4*)out)[r] = o;
}

extern "C" void kernel_launch(void* const* d_in, const int* in_sizes, int n_in,
                              void* d_out, int out_size, void* d_ws, size_t ws_size,
                              hipStream_t stream) {
    const float* ts   = (const float*)d_in[0];
    const float* gyro = (const float*)d_in[1];
    const float* sq   = (const float*)d_in[2];
    const float* W1   = (const float*)d_in[3];
    const float* b1   = (const float*)d_in[4];
    const float* a1   = (const float*)d_in[5];
    const float* W2   = (const float*)d_in[6];
    const float* b2   = (const float*)d_in[7];
    const float* a2   = (const float*)d_in[8];
    float* out = (float*)d_out;

    const int B      = in_sizes[0] / CNT;   // 4096
    const int nitems = B * SEGS;            // 16384
    float4* ws = (float4*)d_ws;             // 256 KB

    pass1_kernel<<<BLOCKS, TPB, 0, stream>>>(ts, gyro, W1, b1, a1, W2, b2, a2, ws, nitems);
    pass2_kernel<<<(B + TPB - 1) / TPB, TPB, 0, stream>>>(ws, sq, out, B);
}